// Round 5
// baseline (184.701 us; speedup 1.0000x reference)
//
#include <hip/hip_runtime.h>

// MessageFunc: out[e,o] = sum_i (relu-MLP(e_vw)[e] . W2[32o+i] + b2[32o+i]) * hw[e,i]
// hw[e,i] = h_w[b, (32*kn+i)//20], e = b*20+kn. For fixed kn, (32*kn+i)//20 takes
// <=3 values -> grouped W2g[kn][g][o][k] (96 cols instead of 1024).
//
// R5: operand-swapped MFMA (W=A-operand -> packed uint2 stage writes) at R2's
// occupancy envelope: biases re-read from LDS per tile (not 56 live VGPRs),
// launch_bounds(256,2), software-pipelined e_vw/h_w prefetch across stages,
// h_w pre-transposed to hwg[kn*3+g][b] for coalesced loads.
// R4 lesson: 196 VGPR + AGPRs > 256/wave -> 1 wave/SIMD -> latency-bound.

typedef __bf16 bf16x8 __attribute__((ext_vector_type(8)));
typedef float  f32x4  __attribute__((ext_vector_type(4)));

#define NB       10000
#define NNEIGH   20
#define PADH     136       // padded LDS row: 272 B (17 x 16B), bank step 4 -> 2-way (free)
#define NCHUNK   25        // blocks per kn; btile = chunk + 25*t; 157 btiles

// ws layout (bytes)
#define WS_W0S   0         // bf16 [8][64][8] A-frag-swizzled W0a (K=32, col16=b0)  8192 B
#define WS_W1B   8192      // bf16 [128][128]                                      32768 B
#define WS_W2G   40960     // bf16 [20][96][128]                                  491520 B
#define WS_B2G   532480    // f32  [20][96]                                         7680 B
#define WS_HWG   540160    // f32  [60][10000]  hwg[(kn*3+g)][b]                 2400000 B

__device__ __forceinline__ unsigned short f2bf(float f) {
    unsigned int u = __float_as_uint(f);
    unsigned int r = (u + 0x7fffu + ((u >> 16) & 1u)) >> 16;
    return (unsigned short)r;
}
__device__ __forceinline__ unsigned int pack2(float a, float b) {
    return (unsigned int)f2bf(a) | ((unsigned int)f2bf(b) << 16);
}

// ---------------- prep ----------------
__global__ __launch_bounds__(256) void prep_kernel(
    const float* __restrict__ W0, const float* __restrict__ b0,
    const float* __restrict__ W1,
    const float* __restrict__ W2, const float* __restrict__ b2,
    const float* __restrict__ h_w,
    unsigned short* __restrict__ w0s, unsigned short* __restrict__ w1b,
    unsigned short* __restrict__ w2g, float* __restrict__ b2g,
    float* __restrict__ hwg)
{
    const int bx = blockIdx.x, tid = threadIdx.x;
    if (bx < 16) {
        // W2g via per-thread prefix sums: thread = (o,k); 32 unrolled loads (ILP),
        // every (kn,g) group sum is a register subtraction.
        int gid = bx * 256 + tid;
        int o = gid >> 7, k = gid & 127;
        float pref[32];
        float run = 0.f;
#pragma unroll
        for (int i = 0; i < 32; ++i) {
            run += W2[(size_t)(32 * o + i) * 128 + k];
            pref[i] = run;
        }
#pragma unroll
        for (int kn = 0; kn < 20; ++kn) {
            const int j0 = (32 * kn) / 20;
#pragma unroll
            for (int g = 0; g < 3; ++g) {
                int lo = 20 * (j0 + g) - 32 * kn;     if (lo < 0) lo = 0;
                int hi = 20 * (j0 + g + 1) - 32 * kn; if (hi > 32) hi = 32;
                float v = (hi > lo) ? (pref[hi - 1] - (lo > 0 ? pref[lo - 1] : 0.f)) : 0.f;
                w2g[((size_t)(kn * 3 + g) * 32 + o) * 128 + k] = f2bf(v);
            }
        }
    } else if (bx == 16) {
        // W0a A-frags: w0s[ct][lane][j] = W0a[ct*16+lq][q*8+j]; col16 = b0, cols>16 = 0
        for (int t = 0; t < 16; ++t) {
            int idx = t * 256 + tid;
            int ct = idx >> 9, lane = (idx >> 3) & 63, j = idx & 7;
            int lq = lane & 15, q = lane >> 4;
            int k = q * 8 + j, o = ct * 16 + lq;
            float v = (k < 16) ? W0[o * 16 + k] : (k == 16 ? b0[o] : 0.f);
            w0s[idx] = f2bf(v);
        }
    } else if (bx <= 32) {
        int base = (bx - 17) * 1024;
        for (int i2 = tid; i2 < 1024; i2 += 256)
            w1b[base + i2] = f2bf(W1[base + i2]);
    } else if (bx == 33) {
        // b2g: 1920 entries
        for (int idx = tid; idx < 1920; idx += 256) {
            int kn = idx / 96, rem = idx - kn * 96;
            int g = rem >> 5, o = rem & 31;
            int j0 = (32 * kn) / 20;
            int lo = 20 * (j0 + g) - 32 * kn;     if (lo < 0) lo = 0;
            int hi = 20 * (j0 + g + 1) - 32 * kn; if (hi > 32) hi = 32;
            float s = 0.f;
            for (int i = lo; i < hi; ++i) s += b2[32 * o + i];
            b2g[idx] = s;
        }
    } else {
        // hwg[(kn*3+g)*10000 + b] = h_w[b*32 + min(j0+g,31)] ; 600000 elems
#pragma unroll
        for (int t = 0; t < 4; ++t) {
            int idx = (bx - 34) * 1024 + t * 256 + tid;
            if (idx < 600000) {
                int kn3 = idx / 10000, b = idx - kn3 * 10000;
                int kn = kn3 / 3, g = kn3 - kn * 3;
                int jv = (32 * kn) / 20 + g; if (jv > 31) jv = 31;
                hwg[idx] = h_w[b * 32 + jv];
            }
        }
    }
}

// ---------------- main fused kernel ----------------
__global__ __launch_bounds__(256, 2) void msg_kernel(
    const float* __restrict__ hwg, const float* __restrict__ e_vw,
    const float* __restrict__ b1v,
    const unsigned short* __restrict__ w0s, const unsigned short* __restrict__ w1b,
    const unsigned short* __restrict__ w2g, const float* __restrict__ b2g,
    float* __restrict__ out)
{
    __shared__ __align__(16) unsigned short sW1[128 * PADH];   // 34816 B
    __shared__ __align__(16) unsigned short sW2g[96 * PADH];   // 26112 B
    __shared__ __align__(16) unsigned short sX[64 * PADH];     // 17408 B
    __shared__ __align__(16) float sB1[128];                   //   512 B
    __shared__ __align__(16) float sB2G[96];                   //   384 B

    const int tid = threadIdx.x;
    const int lane = tid & 63, w = tid >> 6;
    const int quad = lane >> 4, lq = lane & 15;
    const int kn = blockIdx.y, chunk = blockIdx.x;

    // ---- stage W1 + W2g (+biases) into LDS once per block ----
    {
        const uint4* src = (const uint4*)w1b;
        uint4* dst = (uint4*)sW1;
        for (int i = tid; i < 2048; i += 256) { int r = i >> 4, c = i & 15; dst[r * 17 + c] = src[i]; }
    }
    {
        const uint4* src = (const uint4*)(w2g + (size_t)kn * 96 * 128);
        uint4* dst = (uint4*)sW2g;
        for (int i = tid; i < 1536; i += 256) { int r = i >> 4, c = i & 15; dst[r * 17 + c] = src[i]; }
    }
    if (tid < 128) sB1[tid] = b1v[tid];
    if (tid < 96)  sB2G[tid] = b2g[kn * 96 + tid];

    // ---- W0 A-frags in registers (32 VGPRs; coalesced 16B/lane load) ----
    bf16x8 w0f[8];
#pragma unroll
    for (int ct = 0; ct < 8; ++ct)
        w0f[ct] = *(const bf16x8*)(w0s + (ct * 64 + lane) * 8);
    __syncthreads();   // the ONLY barrier

    const int rbase = w * 16;   // wave-private 16-edge strip of sX
    const unsigned short one_bf = 0x3f80;               // bf16(1.0)

    // ---- software-pipeline prologue: load btile 'chunk' ----
    float4 f0, f1;
    float hwv[3];
    {
        const int e = chunk * 64 + rbase + lq;
        if (quad < 2 && e < NB) {
            const float4* p = (const float4*)(e_vw + ((size_t)e * NNEIGH + kn) * 16 + quad * 8);
            f0 = p[0]; f1 = p[1];
        }
#pragma unroll
        for (int g = 0; g < 3; ++g)
            hwv[g] = (e < NB) ? hwg[(kn * 3 + g) * NB + e] : 0.f;
    }

    for (int btile = chunk; btile < 157; btile += NCHUNK) {
        const int e = btile * 64 + rbase + lq;          // this lane's node index

        // ---- convert current B-frag: B[n=lq][k=quad*8+j]; k==16 -> 1.0 (b0 fold) ----
        union { bf16x8 v; uint4 u; } B;
        B.u = make_uint4(0u, 0u, 0u, 0u);
        if (quad < 2) {
            if (e < NB)
                B.u = make_uint4(pack2(f0.x, f0.y), pack2(f0.z, f0.w),
                                 pack2(f1.x, f1.y), pack2(f1.z, f1.w));
        } else if (quad == 2) {
            B.u.x = (unsigned int)one_bf;
        }
        float hw0 = hwv[0], hw1 = hwv[1], hw2 = hwv[2];

        // ---- prefetch next btile (global loads overlap stages A-C) ----
        {
            const int ne = (btile + NCHUNK) * 64 + rbase + lq;
            if (btile + NCHUNK < 157) {
                if (quad < 2 && ne < NB) {
                    const float4* p = (const float4*)(e_vw + ((size_t)ne * NNEIGH + kn) * 16 + quad * 8);
                    f0 = p[0]; f1 = p[1];
                }
#pragma unroll
                for (int g = 0; g < 3; ++g)
                    hwv[g] = (ne < NB) ? hwg[(kn * 3 + g) * NB + ne] : 0.f;
            }
        }

        // ---- stage A: x0 = relu(W0a @ [E|1]) ; D row=feature, col=edge ----
#pragma unroll
        for (int ct = 0; ct < 8; ++ct) {
            f32x4 acc = {0.f, 0.f, 0.f, 0.f};
            acc = __builtin_amdgcn_mfma_f32_16x16x32_bf16(w0f[ct], B.v, acc, 0, 0, 0);
#pragma unroll
            for (int r2 = 0; r2 < 4; ++r2) acc[r2] = acc[r2] > 0.f ? acc[r2] : 0.f;
            uint2 pk = make_uint2(pack2(acc[0], acc[1]), pack2(acc[2], acc[3]));
            *(uint2*)&sX[(rbase + lq) * PADH + ct * 16 + quad * 4] = pk;
        }

        // ---- stage B: x1 = relu(W1 @ x0 + b1), K=128, in-place on sX ----
        {
            bf16x8 xf[4];
#pragma unroll
            for (int ka = 0; ka < 4; ++ka)
                xf[ka] = *(const bf16x8*)&sX[(rbase + lq) * PADH + ka * 32 + quad * 8];
#pragma unroll
            for (int ct = 0; ct < 8; ++ct) {
                f32x4 acc = *(const f32x4*)&sB1[ct * 16 + quad * 4];
#pragma unroll
                for (int ka = 0; ka < 4; ++ka) {
                    bf16x8 wf = *(const bf16x8*)&sW1[(ct * 16 + lq) * PADH + ka * 32 + quad * 8];
                    acc = __builtin_amdgcn_mfma_f32_16x16x32_bf16(wf, xf[ka], acc, 0, 0, 0);
                }
#pragma unroll
                for (int r2 = 0; r2 < 4; ++r2) acc[r2] = acc[r2] > 0.f ? acc[r2] : 0.f;
                uint2 pk = make_uint2(pack2(acc[0], acc[1]), pack2(acc[2], acc[3]));
                *(uint2*)&sX[(rbase + lq) * PADH + ct * 16 + quad * 4] = pk;
            }
        }

        // ---- stage C: G = W2g @ x1 + b2g (96 rows), then h_w contraction ----
        {
            bf16x8 xf[4];
#pragma unroll
            for (int ka = 0; ka < 4; ++ka)
                xf[ka] = *(const bf16x8*)&sX[(rbase + lq) * PADH + ka * 32 + quad * 8];
            f32x4 accC[6];
#pragma unroll
            for (int ct = 0; ct < 6; ++ct) {
                f32x4 acc = *(const f32x4*)&sB2G[ct * 16 + quad * 4];
#pragma unroll
                for (int ka = 0; ka < 4; ++ka) {
                    bf16x8 wf = *(const bf16x8*)&sW2g[(ct * 16 + lq) * PADH + ka * 32 + quad * 8];
                    acc = __builtin_amdgcn_mfma_f32_16x16x32_bf16(wf, xf[ka], acc, 0, 0, 0);
                }
                accC[ct] = acc;
            }
            // lane holds G rows c = ct*16+quad*4+r2 for its edge (col=lq);
            // c = g*32 + o, o = half*16+quad*4+r2, ct = g*2+half.
            if (e < NB) {
#pragma unroll
                for (int half = 0; half < 2; ++half) {
                    float4 val;
                    float* vp = &val.x;
#pragma unroll
                    for (int r2 = 0; r2 < 4; ++r2)
                        vp[r2] = hw0 * accC[half][r2] + hw1 * accC[2 + half][r2]
                               + hw2 * accC[4 + half][r2];
                    *(float4*)(out + ((size_t)e * NNEIGH + kn) * 32 + half * 16 + quad * 4) = val;
                }
            }
        }
    }
}

extern "C" void kernel_launch(void* const* d_in, const int* in_sizes, int n_in,
                              void* d_out, int out_size, void* d_ws, size_t ws_size,
                              hipStream_t stream)
{
    // setup_inputs order: h_v, h_w, e_vw, W0, b0, W1, b1, W2, b2  (all float32)
    const float* h_w = (const float*)d_in[1];
    const float* e_vw = (const float*)d_in[2];
    const float* W0 = (const float*)d_in[3];
    const float* b0 = (const float*)d_in[4];
    const float* W1 = (const float*)d_in[5];
    const float* b1 = (const float*)d_in[6];
    const float* W2 = (const float*)d_in[7];
    const float* b2 = (const float*)d_in[8];
    float* out = (float*)d_out;

    char* ws = (char*)d_ws;
    unsigned short* w0s = (unsigned short*)(ws + WS_W0S);
    unsigned short* w1b = (unsigned short*)(ws + WS_W1B);
    unsigned short* w2g = (unsigned short*)(ws + WS_W2G);
    float*          b2g = (float*)(ws + WS_B2G);
    float*          hwg = (float*)(ws + WS_HWG);

    prep_kernel<<<34 + 586, 256, 0, stream>>>(W0, b0, W1, W2, b2, h_w,
                                              w0s, w1b, w2g, b2g, hwg);
    dim3 grid(NCHUNK, 20);
    msg_kernel<<<grid, 256, 0, stream>>>(hwg, e_vw, b1, w0s, w1b, w2g, b2g, out);
}

// Round 6
// 132.964 us; speedup vs baseline: 1.3891x; 1.3891x over previous
//
#include <hip/hip_runtime.h>

// MessageFunc: out[e,o] = sum_i (relu-MLP(e_vw)[e] . W2[32o+i] + b2[32o+i]) * hw[e,i]
// hw[e,i] = h_w[b, (32*kn+i)//20], e = b*20+kn. For fixed kn, (32*kn+i)//20 takes
// 2..3 values -> grouped W2g[kn][g][o][k] (<=96 cols instead of 1024).
//
// R6: operand-swapped MFMA (W=A -> packed uint2 stage writes), biases re-read
// from LDS per tile, NO launch_bounds min-waves clamp. Register ledger (m69:
// 512 regs/SIMD, VGPR+AGPR unified): R4 = 196V + ~64A = 260 > 256 -> 1 wave/SIMD;
// clamping to 128 (R3/R5) forced scratch spill (190 MB FETCH). Cutting the 56
// bias VGPRs lands ~205 total -> 2 waves/SIMD naturally, no spill.
// Also: per-kn group count (12 of 20 kn have only 2 h_w groups) skips 1/3 of
// stage C on those blocks.

typedef __bf16 bf16x8 __attribute__((ext_vector_type(8)));
typedef float  f32x4  __attribute__((ext_vector_type(4)));

#define NB       10000
#define NNEIGH   20
#define PADH     136       // padded LDS row: 272 B (17 x 16B), bank step 4 -> 2-way (free)
#define NCHUNK   25        // blocks per kn; btile = chunk + 25*t; 157 btiles

// ws layout (bytes)
#define WS_W0S   0         // bf16 [8][64][8] A-frag-swizzled W0a (K=32, col16=b0)  8192 B
#define WS_W1B   8192      // bf16 [128][128]                                      32768 B
#define WS_W2G   40960     // bf16 [20][96][128]                                  491520 B
#define WS_B2G   532480    // f32  [20][96]                                         7680 B
#define WS_HWG   540160    // f32  [60][10000]  hwg[(kn*3+g)][b]                 2400000 B

__device__ __forceinline__ unsigned short f2bf(float f) {
    unsigned int u = __float_as_uint(f);
    unsigned int r = (u + 0x7fffu + ((u >> 16) & 1u)) >> 16;
    return (unsigned short)r;
}
__device__ __forceinline__ unsigned int pack2(float a, float b) {
    return (unsigned int)f2bf(a) | ((unsigned int)f2bf(b) << 16);
}

// ---------------- prep ----------------
__global__ __launch_bounds__(256) void prep_kernel(
    const float* __restrict__ W0, const float* __restrict__ b0,
    const float* __restrict__ W1,
    const float* __restrict__ W2, const float* __restrict__ b2,
    const float* __restrict__ h_w,
    unsigned short* __restrict__ w0s, unsigned short* __restrict__ w1b,
    unsigned short* __restrict__ w2g, float* __restrict__ b2g,
    float* __restrict__ hwg)
{
    const int bx = blockIdx.x, tid = threadIdx.x;
    if (bx < 16) {
        // W2g via per-thread prefix sums: thread = (o,k); 32 unrolled loads (ILP),
        // every (kn,g) group sum is a register subtraction.
        int gid = bx * 256 + tid;
        int o = gid >> 7, k = gid & 127;
        float pref[32];
        float run = 0.f;
#pragma unroll
        for (int i = 0; i < 32; ++i) {
            run += W2[(size_t)(32 * o + i) * 128 + k];
            pref[i] = run;
        }
#pragma unroll
        for (int kn = 0; kn < 20; ++kn) {
            const int j0 = (32 * kn) / 20;
#pragma unroll
            for (int g = 0; g < 3; ++g) {
                int lo = 20 * (j0 + g) - 32 * kn;     if (lo < 0) lo = 0;
                int hi = 20 * (j0 + g + 1) - 32 * kn; if (hi > 32) hi = 32;
                float v = (hi > lo) ? (pref[hi - 1] - (lo > 0 ? pref[lo - 1] : 0.f)) : 0.f;
                w2g[((size_t)(kn * 3 + g) * 32 + o) * 128 + k] = f2bf(v);
            }
        }
    } else if (bx == 16) {
        // W0a A-frags: w0s[ct][lane][j] = W0a[ct*16+lq][q*8+j]; col16 = b0, cols>16 = 0
        for (int t = 0; t < 16; ++t) {
            int idx = t * 256 + tid;
            int ct = idx >> 9, lane = (idx >> 3) & 63, j = idx & 7;
            int lq = lane & 15, q = lane >> 4;
            int k = q * 8 + j, o = ct * 16 + lq;
            float v = (k < 16) ? W0[o * 16 + k] : (k == 16 ? b0[o] : 0.f);
            w0s[idx] = f2bf(v);
        }
    } else if (bx <= 32) {
        int base = (bx - 17) * 1024;
        for (int i2 = tid; i2 < 1024; i2 += 256)
            w1b[base + i2] = f2bf(W1[base + i2]);
    } else if (bx == 33) {
        // b2g: 1920 entries
        for (int idx = tid; idx < 1920; idx += 256) {
            int kn = idx / 96, rem = idx - kn * 96;
            int g = rem >> 5, o = rem & 31;
            int j0 = (32 * kn) / 20;
            int lo = 20 * (j0 + g) - 32 * kn;     if (lo < 0) lo = 0;
            int hi = 20 * (j0 + g + 1) - 32 * kn; if (hi > 32) hi = 32;
            float s = 0.f;
            for (int i = lo; i < hi; ++i) s += b2[32 * o + i];
            b2g[idx] = s;
        }
    } else {
        // hwg[(kn*3+g)*10000 + b] = h_w[b*32 + min(j0+g,31)] ; 600000 elems
#pragma unroll
        for (int t = 0; t < 4; ++t) {
            int idx = (bx - 34) * 1024 + t * 256 + tid;
            if (idx < 600000) {
                int kn3 = idx / 10000, b = idx - kn3 * 10000;
                int kn = kn3 / 3, g = kn3 - kn * 3;
                int jv = (32 * kn) / 20 + g; if (jv > 31) jv = 31;
                hwg[idx] = h_w[b * 32 + jv];
            }
        }
    }
}

// ---------------- main fused kernel ----------------
__global__ __launch_bounds__(256) void msg_kernel(
    const float* __restrict__ hwg, const float* __restrict__ e_vw,
    const float* __restrict__ b1v,
    const unsigned short* __restrict__ w0s, const unsigned short* __restrict__ w1b,
    const unsigned short* __restrict__ w2g, const float* __restrict__ b2g,
    float* __restrict__ out)
{
    __shared__ __align__(16) unsigned short sW1[128 * PADH];   // 34816 B
    __shared__ __align__(16) unsigned short sW2g[96 * PADH];   // 26112 B
    __shared__ __align__(16) unsigned short sX[64 * PADH];     // 17408 B
    __shared__ __align__(16) float sB1[128];                   //   512 B
    __shared__ __align__(16) float sB2G[96];                   //   384 B

    const int tid = threadIdx.x;
    const int lane = tid & 63, w = tid >> 6;
    const int quad = lane >> 4, lq = lane & 15;
    const int kn = blockIdx.y, chunk = blockIdx.x;
    // number of active h_w groups for this kn: 2 or 3 (group 2 is all-zero when 2)
    const bool three = ((32 * kn) % 20) > 8;   // r in {12,16} -> 3 groups; {0,4,8} -> 2

    // ---- stage W1 + W2g (+biases) into LDS once per block ----
    {
        const uint4* src = (const uint4*)w1b;
        uint4* dst = (uint4*)sW1;
        for (int i = tid; i < 2048; i += 256) { int r = i >> 4, c = i & 15; dst[r * 17 + c] = src[i]; }
    }
    {
        const int n4 = three ? 1536 : 1024;    // skip zero group-2 rows when absent
        const uint4* src = (const uint4*)(w2g + (size_t)kn * 96 * 128);
        uint4* dst = (uint4*)sW2g;
        for (int i = tid; i < n4; i += 256) { int r = i >> 4, c = i & 15; dst[r * 17 + c] = src[i]; }
    }
    if (tid < 128) sB1[tid] = b1v[tid];
    if (tid < 96)  sB2G[tid] = b2g[kn * 96 + tid];

    // ---- W0 A-frags in registers (32 VGPRs; coalesced 16B/lane load) ----
    bf16x8 w0f[8];
#pragma unroll
    for (int ct = 0; ct < 8; ++ct)
        w0f[ct] = *(const bf16x8*)(w0s + (ct * 64 + lane) * 8);
    __syncthreads();   // the ONLY barrier

    const int rbase = w * 16;   // wave-private 16-edge strip of sX
    const unsigned short one_bf = 0x3f80;               // bf16(1.0)

    // ---- software-pipeline prologue: load btile 'chunk' ----
    float4 f0, f1;
    float hwv[3];
    {
        const int e = chunk * 64 + rbase + lq;
        if (quad < 2 && e < NB) {
            const float4* p = (const float4*)(e_vw + ((size_t)e * NNEIGH + kn) * 16 + quad * 8);
            f0 = p[0]; f1 = p[1];
        }
        hwv[0] = (e < NB) ? hwg[(kn * 3 + 0) * NB + e] : 0.f;
        hwv[1] = (e < NB) ? hwg[(kn * 3 + 1) * NB + e] : 0.f;
        hwv[2] = (three && e < NB) ? hwg[(kn * 3 + 2) * NB + e] : 0.f;
    }

    for (int btile = chunk; btile < 157; btile += NCHUNK) {
        const int e = btile * 64 + rbase + lq;          // this lane's node index

        // ---- convert current B-frag: B[n=lq][k=quad*8+j]; k==16 -> 1.0 (b0 fold) ----
        union { bf16x8 v; uint4 u; } B;
        B.u = make_uint4(0u, 0u, 0u, 0u);
        if (quad < 2) {
            if (e < NB)
                B.u = make_uint4(pack2(f0.x, f0.y), pack2(f0.z, f0.w),
                                 pack2(f1.x, f1.y), pack2(f1.z, f1.w));
        } else if (quad == 2) {
            B.u.x = (unsigned int)one_bf;
        }
        float hw0 = hwv[0], hw1 = hwv[1], hw2 = hwv[2];

        // ---- prefetch next btile (global loads overlap stages A-C) ----
        {
            const int ne = (btile + NCHUNK) * 64 + rbase + lq;
            if (btile + NCHUNK < 157) {
                if (quad < 2 && ne < NB) {
                    const float4* p = (const float4*)(e_vw + ((size_t)ne * NNEIGH + kn) * 16 + quad * 8);
                    f0 = p[0]; f1 = p[1];
                }
                hwv[0] = (ne < NB) ? hwg[(kn * 3 + 0) * NB + ne] : 0.f;
                hwv[1] = (ne < NB) ? hwg[(kn * 3 + 1) * NB + ne] : 0.f;
                hwv[2] = (three && ne < NB) ? hwg[(kn * 3 + 2) * NB + ne] : 0.f;
            }
        }

        // ---- stage A: x0 = relu(W0a @ [E|1]) ; D row=feature, col=edge ----
#pragma unroll
        for (int ct = 0; ct < 8; ++ct) {
            f32x4 acc = {0.f, 0.f, 0.f, 0.f};
            acc = __builtin_amdgcn_mfma_f32_16x16x32_bf16(w0f[ct], B.v, acc, 0, 0, 0);
#pragma unroll
            for (int r2 = 0; r2 < 4; ++r2) acc[r2] = acc[r2] > 0.f ? acc[r2] : 0.f;
            uint2 pk = make_uint2(pack2(acc[0], acc[1]), pack2(acc[2], acc[3]));
            *(uint2*)&sX[(rbase + lq) * PADH + ct * 16 + quad * 4] = pk;
        }

        // ---- stage B: x1 = relu(W1 @ x0 + b1), K=128, in-place on sX ----
        {
            bf16x8 xf[4];
#pragma unroll
            for (int ka = 0; ka < 4; ++ka)
                xf[ka] = *(const bf16x8*)&sX[(rbase + lq) * PADH + ka * 32 + quad * 8];
#pragma unroll
            for (int ct = 0; ct < 8; ++ct) {
                f32x4 acc = *(const f32x4*)&sB1[ct * 16 + quad * 4];
#pragma unroll
                for (int ka = 0; ka < 4; ++ka) {
                    bf16x8 wf = *(const bf16x8*)&sW1[(ct * 16 + lq) * PADH + ka * 32 + quad * 8];
                    acc = __builtin_amdgcn_mfma_f32_16x16x32_bf16(wf, xf[ka], acc, 0, 0, 0);
                }
#pragma unroll
                for (int r2 = 0; r2 < 4; ++r2) acc[r2] = acc[r2] > 0.f ? acc[r2] : 0.f;
                uint2 pk = make_uint2(pack2(acc[0], acc[1]), pack2(acc[2], acc[3]));
                *(uint2*)&sX[(rbase + lq) * PADH + ct * 16 + quad * 4] = pk;
            }
        }

        // ---- stage C: G = W2g @ x1 + b2g (64 or 96 rows), then h_w contraction ----
        {
            bf16x8 xf[4];
#pragma unroll
            for (int ka = 0; ka < 4; ++ka)
                xf[ka] = *(const bf16x8*)&sX[(rbase + lq) * PADH + ka * 32 + quad * 8];
            f32x4 accC[6];
#pragma unroll
            for (int ct = 0; ct < 4; ++ct) {
                f32x4 acc = *(const f32x4*)&sB2G[ct * 16 + quad * 4];
#pragma unroll
                for (int ka = 0; ka < 4; ++ka) {
                    bf16x8 wf = *(const bf16x8*)&sW2g[(ct * 16 + lq) * PADH + ka * 32 + quad * 8];
                    acc = __builtin_amdgcn_mfma_f32_16x16x32_bf16(wf, xf[ka], acc, 0, 0, 0);
                }
                accC[ct] = acc;
            }
            if (three) {
#pragma unroll
                for (int ct = 4; ct < 6; ++ct) {
                    f32x4 acc = *(const f32x4*)&sB2G[ct * 16 + quad * 4];
#pragma unroll
                    for (int ka = 0; ka < 4; ++ka) {
                        bf16x8 wf = *(const bf16x8*)&sW2g[(ct * 16 + lq) * PADH + ka * 32 + quad * 8];
                        acc = __builtin_amdgcn_mfma_f32_16x16x32_bf16(wf, xf[ka], acc, 0, 0, 0);
                    }
                    accC[ct] = acc;
                }
            }
            // lane holds G rows c = ct*16+quad*4+r2 for its edge (col=lq);
            // c = g*32 + o, o = half*16+quad*4+r2, ct = g*2+half.
            if (e < NB) {
#pragma unroll
                for (int half = 0; half < 2; ++half) {
                    float4 val;
                    float* vp = &val.x;
#pragma unroll
                    for (int r2 = 0; r2 < 4; ++r2) {
                        float s = hw0 * accC[half][r2] + hw1 * accC[2 + half][r2];
                        if (three) s += hw2 * accC[4 + half][r2];
                        vp[r2] = s;
                    }
                    *(float4*)(out + ((size_t)e * NNEIGH + kn) * 32 + half * 16 + quad * 4) = val;
                }
            }
        }
    }
}

extern "C" void kernel_launch(void* const* d_in, const int* in_sizes, int n_in,
                              void* d_out, int out_size, void* d_ws, size_t ws_size,
                              hipStream_t stream)
{
    // setup_inputs order: h_v, h_w, e_vw, W0, b0, W1, b1, W2, b2  (all float32)
    const float* h_w = (const float*)d_in[1];
    const float* e_vw = (const float*)d_in[2];
    const float* W0 = (const float*)d_in[3];
    const float* b0 = (const float*)d_in[4];
    const float* W1 = (const float*)d_in[5];
    const float* b1 = (const float*)d_in[6];
    const float* W2 = (const float*)d_in[7];
    const float* b2 = (const float*)d_in[8];
    float* out = (float*)d_out;

    char* ws = (char*)d_ws;
    unsigned short* w0s = (unsigned short*)(ws + WS_W0S);
    unsigned short* w1b = (unsigned short*)(ws + WS_W1B);
    unsigned short* w2g = (unsigned short*)(ws + WS_W2G);
    float*          b2g = (float*)(ws + WS_B2G);
    float*          hwg = (float*)(ws + WS_HWG);

    prep_kernel<<<34 + 586, 256, 0, stream>>>(W0, b0, W1, W2, b2, h_w,
                                              w0s, w1b, w2g, b2g, hwg);
    dim3 grid(NCHUNK, 20);
    msg_kernel<<<grid, 256, 0, stream>>>(hwg, e_vw, b1, w0s, w1b, w2g, b2g, out);
}